// Round 14
// baseline (38.840 us; speedup 1.0000x reference)
//
#include <hip/hip_runtime.h>

// Ray-sphere intersection: N rays x 64 moving spheres -> closest hit distance.
// x: (1, N, 7) f32 = [origin(3), t_ray(1), direction(3)]
// z: (1, 384) f32 = 64 spheres x [center(3), velocity(3)]
// out: mu (N) ++ sigma (N), f32
//
// R14: LEAN SCALAR body. Measured invariant across R2-R13: packed (VOP3P-
// dense) streams issue at ~57-60% efficiency regardless of ILP/occupancy/
// staging/block-size; scalar streams (R2, R11) issue at ~83%. Packed ops are
// 4 cyc vs scalar 2 (fp32 rate fixed) -> cycles/ray equal -> lean scalar at
// 0.83 should win: ~22 VALU+1 TRANS per ray-sphere = ~48 cyc/step, ~20.5us
// busy, ~25us at eta=0.83. R2 also showed scatter x-loads don't depress
// scalar eta -> no LDS staging, minimal code.
//
// FROZEN ARITHMETIC (proven R3/R5/R8 + scalar form R10-R13):
//   oc = fmaf(v,t, c-o); b = fmaf(dx,ocx,fmaf(dy,ocy,dz*ocz));
//   csq = fmaf(ocx,ocx,fmaf(ocy,ocy,ocz*ocz)); disc = fmaf(b,b, 1.0f-csq);
//   sq = raw v_sqrt(disc) (disc<0 -> NaN -> compares false -> BIG);
//   r = t0>0 ? t0 : (t1>0 ? t1 : BIG); closest = fminf(closest, r).
// Unsigned-bit-min tails are BANNED (failed R4, R7).

constexpr float BIGF = 1e10f;

__global__ __launch_bounds__(256, 8) void ray_sphere_kernel(
    const float* __restrict__ x, const float* __restrict__ z,
    float* __restrict__ out, int N)
{
    int n = blockIdx.x * 256 + threadIdx.x;   // 1 ray per thread

    const float* xr = x + (long)n * 7;
    float ox = xr[0], oy = xr[1], oz = xr[2];
    float tr = xr[3];
    float dx = xr[4], dy = xr[5], dz = xr[6];

    // normalize d: d / (sqrt(|d|^2) + 1e-12)   (FROZEN)
    {
        float n2 = fmaf(dx, dx, fmaf(dy, dy, dz * dz));
        float inv = __builtin_amdgcn_rcpf(__builtin_amdgcn_sqrtf(n2) + 1e-12f);
        dx *= inv; dy *= inv; dz *= inv;
    }

    float closest = BIGF;

    #pragma unroll 8
    for (int s = 0; s < 64; ++s) {
        const float* zs = z + s * 6;          // uniform -> s_load, SGPR
        float cx = zs[0], cy = zs[1], cz = zs[2];
        float vx = zs[3], vy = zs[4], vz = zs[5];

        // FROZEN chain (22 VALU + 1 TRANS)
        float ocx = fmaf(vx, tr, cx - ox);
        float ocy = fmaf(vy, tr, cy - oy);
        float ocz = fmaf(vz, tr, cz - oz);
        float b   = fmaf(dx, ocx, fmaf(dy, ocy, dz * ocz));
        float csq = fmaf(ocx, ocx, fmaf(ocy, ocy, ocz * ocz));
        float disc = fmaf(b, b, 1.0f - csq);
        float sq = __builtin_amdgcn_sqrtf(disc);   // disc<0 -> NaN -> BIG
        float t0 = b - sq, t1 = b + sq;
        float r1 = (t1 > 0.0f) ? t1 : BIGF;
        float r  = (t0 > 0.0f) ? t0 : r1;
        closest = fminf(closest, r);
    }

    out[n]     = closest;    // coalesced dword stores
    out[N + n] = 0.002f;
}

extern "C" void kernel_launch(void* const* d_in, const int* in_sizes, int n_in,
                              void* d_out, int out_size, void* d_ws, size_t ws_size,
                              hipStream_t stream) {
    const float* x = (const float*)d_in[0];
    const float* z = (const float*)d_in[1];
    float* out = (float*)d_out;
    int N = in_sizes[0] / 7;   // 1048576

    int blocks = N / 256;      // 4096
    ray_sphere_kernel<<<blocks, 256, 0, stream>>>(x, z, out, N);
}

// Round 15
// 34.325 us; speedup vs baseline: 1.1315x; 1.1315x over previous
//
#include <hip/hip_runtime.h>

// Ray-sphere intersection: N rays x 64 moving spheres -> closest hit distance.
// x: (1, N, 7) f32 = [origin(3), t_ray(1), direction(3)]
// z: (1, 384) f32 = 64 spheres x [center(3), velocity(3)]
// out: mu (N) ++ sigma (N), f32
//
// FINAL (R8 restoration, measured 34.3us = session best).
// Session ledger: packed v2f core (v_pk_fma_f32, 2 rays/thread) has busy
// cost ~0.70 cyc*SIMD per ray-sphere pair (hand count == measured, no fat);
// issue efficiency for VOP3P-dense streams caps at ~0.56-0.60 invariant to
// occupancy (16/32 waves/CU), ILP (2/4 rays), operand staging (K$/LDS),
// sphere stagger, split-K, and block size (R5-R13 all null vs R8). Scalar
// streams reach eta~0.84 but cost 1.19 cyc/pair busy -> worse wall (R14).
// Both routes converge to ~34-39us; R8 is the measured optimum.
//
// FROZEN ARITHMETIC (R3/R5/R8-proven): oc/b/csq chains, normalize, and
// disc = fma(b,b, 1.0f - csq). 1-ulp re-associations flip tangent-boundary
// pairs vs the reference (R4: one flip = 1e10 error). Raw v_sqrt NaN path:
// disc<0 -> NaN -> ordered compares false -> BIG. Unsigned-bit-min tails
// BANNED (failed R4, R7); select tail proven.

typedef float v2f __attribute__((ext_vector_type(2)));

constexpr float BIGF = 1e10f;

__global__ __launch_bounds__(256, 8) void ray_sphere_kernel(
    const float* __restrict__ x, const float* __restrict__ z,
    float* __restrict__ out, int N)
{
    int tid = blockIdx.x * 256 + threadIdx.x;
    long n0 = (long)tid * 2;                      // 2 rays per thread
    if (n0 >= N) return;

    // 14 consecutive floats, 8B-aligned (tid*56B) -> 7x global_load_dwordx2
    const float2* xr = (const float2*)(x + n0 * 7);
    float2 w0 = xr[0], w1 = xr[1], w2 = xr[2], w3 = xr[3],
           w4 = xr[4], w5 = xr[5], w6 = xr[6];

    v2f ox = {w0.x, w3.y}, oy = {w0.y, w4.x}, oz = {w1.x, w4.y};
    v2f t  = {w1.y, w5.x};
    v2f dx = {w2.x, w5.y}, dy = {w2.y, w6.x}, dz = {w3.x, w6.y};

    // normalize d: d / (sqrt(|d|^2) + 1e-12)   (FROZEN)
    {
        v2f n2 = __builtin_elementwise_fma(dx, dx,
                 __builtin_elementwise_fma(dy, dy, dz * dz));
        v2f inv;
        inv[0] = __builtin_amdgcn_rcpf(__builtin_amdgcn_sqrtf(n2[0]) + 1e-12f);
        inv[1] = __builtin_amdgcn_rcpf(__builtin_amdgcn_sqrtf(n2[1]) + 1e-12f);
        dx *= inv; dy *= inv; dz *= inv;
    }

    v2f closest = {BIGF, BIGF};

    int s0 = (blockIdx.x & 7) << 3;   // block phase: sphere start 0,8,...,56

    #pragma unroll
    for (int j = 0; j < 8; ++j) {
        // group base: runtime SGPR, affine inner range -> batched s_loads
        const float* zg = z + ((s0 + (j << 3)) & 63) * 6;
        #pragma unroll
        for (int k = 0; k < 8; ++k) {
            const float* zs = zg + k * 6;
            float cx = zs[0], cy = zs[1], cz = zs[2];
            float vx = zs[3], vy = zs[4], vz = zs[5];

            // oc = (c - o) + v * t               (FROZEN)
            v2f ocx = __builtin_elementwise_fma((v2f){vx, vx}, t, cx - ox);
            v2f ocy = __builtin_elementwise_fma((v2f){vy, vy}, t, cy - oy);
            v2f ocz = __builtin_elementwise_fma((v2f){vz, vz}, t, cz - oz);
            // b = d . oc                         (FROZEN)
            v2f b = __builtin_elementwise_fma(dx, ocx,
                    __builtin_elementwise_fma(dy, ocy, dz * ocz));
            // csq = |oc|^2                       (FROZEN)
            v2f csq = __builtin_elementwise_fma(ocx, ocx,
                      __builtin_elementwise_fma(ocy, ocy, ocz * ocz));
            // disc = b^2 + (1 - csq)             (FROZEN)
            v2f disc = __builtin_elementwise_fma(b, b, (v2f){1.0f, 1.0f} - csq);

            // disc<0 -> NaN -> both compares below false -> BIG
            v2f sq;
            sq[0] = __builtin_amdgcn_sqrtf(disc[0]);
            sq[1] = __builtin_amdgcn_sqrtf(disc[1]);

            v2f t0 = b - sq;
            v2f t1 = b + sq;

            #pragma unroll
            for (int kk = 0; kk < 2; ++kk) {
                float r1 = (t1[kk] > 0.0f) ? t1[kk] : BIGF;   // cmp + cndmask
                float r  = (t0[kk] > 0.0f) ? t0[kk] : r1;     // cmp + cndmask
                closest[kk] = fminf(closest[kk], r);          // v_min
            }
        }
    }

    *(float2*)(out + n0) = make_float2(closest[0], closest[1]);
    *(float2*)(out + N + n0) = make_float2(0.002f, 0.002f);
}

extern "C" void kernel_launch(void* const* d_in, const int* in_sizes, int n_in,
                              void* d_out, int out_size, void* d_ws, size_t ws_size,
                              hipStream_t stream) {
    const float* x = (const float*)d_in[0];
    const float* z = (const float*)d_in[1];
    float* out = (float*)d_out;
    int N = in_sizes[0] / 7;   // 1048576

    int threads = N / 2;
    int blocks = (threads + 255) / 256;   // 2048
    ray_sphere_kernel<<<blocks, 256, 0, stream>>>(x, z, out, N);
}